// Round 2
// baseline (298.573 us; speedup 1.0000x reference)
//
#include <hip/hip_runtime.h>
#include <math.h>

namespace {
constexpr int N = 8, C = 48, H = 96, W = 72;
constexpr int HW = H * W;        // 6912
constexpr int P = N * HW;        // 55296
constexpr float BN_EPS = 1e-5f;

// ws layout (float offsets)
constexpr int WS_OY   = 0;            // 9 planes of P
constexpr int WS_OX   = 9 * P;
constexpr int WS_MK   = 18 * P;
constexpr int WS_WCAT = 27 * P;       // wcat[c][t][16]: 0..3 tm, 4..5 tr, 6..14 mk, 15 pad
constexpr int WCAT_SZ = C * 9 * 16;   // 6912
constexpr int WS_DWT  = WS_WCAT + WCAT_SZ;   // dwT[k][c][o], o contiguous
constexpr int DWT_SZ  = 9 * C * C;    // 20736
}

// ---------------------------------------------------------------------------
// Weight re-layout so hot loops read wave-uniform contiguous vectors (s_load).
// ---------------------------------------------------------------------------
__global__ void prep_kernel(const float* __restrict__ tm_w, const float* __restrict__ tr_w,
                            const float* __restrict__ mk_w, const float* __restrict__ dw,
                            float* __restrict__ ws)
{
    int tid = blockIdx.x * blockDim.x + threadIdx.x;

    if (tid < WCAT_SZ) {
        int o  = tid & 15;
        int ct = tid >> 4;         // c*9 + t
        int c  = ct / 9;
        int t  = ct - c * 9;
        float v = 0.f;
        if (o < 4)       v = tm_w[(o * C + c) * 9 + t];
        else if (o < 6)  v = tr_w[((o - 4) * C + c) * 9 + t];
        else if (o < 15) v = mk_w[((o - 6) * C + c) * 9 + t];
        ws[WS_WCAT + tid] = v;
    }
    if (tid < DWT_SZ) {
        int o    = tid % C;
        int rest = tid / C;        // k*C + c
        int c    = rest % C;
        int k    = rest / C;
        ws[WS_DWT + tid] = dw[(o * C + c) * 9 + k];
    }
}

// ---------------------------------------------------------------------------
// Kernel A: 15-channel 3x3 conv -> oy/ox/mask planes (SoA in ws)
// ---------------------------------------------------------------------------
__global__ __launch_bounds__(256) void conv15_kernel(
    const float* __restrict__ x,
    const float* __restrict__ tm_b, const float* __restrict__ tr_b,
    const float* __restrict__ mk_b,
    float* __restrict__ ws)
{
    const float* wcat = ws + WS_WCAT;

    int pid = blockIdx.x * 256 + threadIdx.x;
    if (pid >= P) return;
    int n  = pid / HW;
    int hw = pid - n * HW;
    int h  = hw / W;
    int w  = hw - h * W;

    float acc[15];
#pragma unroll
    for (int o = 0; o < 15; ++o) acc[o] = 0.f;

    const float* xn = x + (size_t)n * C * HW;

#pragma unroll 2
    for (int c = 0; c < C; ++c) {
        const float* xc = xn + c * HW;
        float tap[9];
#pragma unroll
        for (int dy = -1; dy <= 1; ++dy) {
            int hh = h + dy;
            bool vy = (unsigned)hh < (unsigned)H;
#pragma unroll
            for (int dx = -1; dx <= 1; ++dx) {
                int ww = w + dx;
                bool v = vy && ((unsigned)ww < (unsigned)W);
                tap[(dy + 1) * 3 + (dx + 1)] = v ? xc[hh * W + ww] : 0.f;
            }
        }
#pragma unroll
        for (int t = 0; t < 9; ++t) {
            const float* wp = wcat + (c * 9 + t) * 16;   // 64B aligned, uniform
            float tv = tap[t];
#pragma unroll
            for (int o = 0; o < 15; ++o) acc[o] = fmaf(tv, wp[o], acc[o]);
        }
    }

    float t0 = acc[0] + tm_b[0], t1 = acc[1] + tm_b[1];
    float t2 = acc[2] + tm_b[2], t3 = acc[3] + tm_b[3];
    float r0 = acc[4] + tr_b[0], r1 = acc[5] + tr_b[1];

#pragma unroll
    for (int k = 0; k < 9; ++k) {
        float ry = (float)(k / 3) - 1.f;
        float rx = (float)(k % 3) - 1.f;
        // oy = t0*ry + t1*rx - ry + tr0 ; ox = t2*ry + t3*rx - rx + tr1
        ws[WS_OY + k * P + pid] = fmaf(t0, ry, fmaf(t1, rx, r0)) - ry;
        ws[WS_OX + k * P + pid] = fmaf(t2, ry, fmaf(t3, rx, r1)) - rx;
        ws[WS_MK + k * P + pid] = acc[6 + k] + mk_b[k];
    }
}

// ---------------------------------------------------------------------------
// Kernel B: bilinear deform-sample + 48x(48*9) contraction + BN + res + ReLU
// ---------------------------------------------------------------------------
__global__ __launch_bounds__(256) void deform_kernel(
    const float* __restrict__ x, const float* __restrict__ ws,
    const float* __restrict__ gamma, const float* __restrict__ beta,
    const float* __restrict__ rmean, const float* __restrict__ rvar,
    float* __restrict__ out)
{
    int pid = blockIdx.x * 256 + threadIdx.x;
    if (pid >= P) return;
    int n  = pid / HW;
    int hw = pid - n * HW;
    int h  = hw / W;
    int w  = hw - h * W;

    float acc[C];
#pragma unroll
    for (int o = 0; o < C; ++o) acc[o] = 0.f;

    const float* xn  = x + (size_t)n * C * HW;
    const float* dwT = ws + WS_DWT;

#pragma unroll 1
    for (int k = 0; k < 9; ++k) {
        float o_y = ws[WS_OY + k * P + pid];
        float o_x = ws[WS_OX + k * P + pid];
        float m   = ws[WS_MK + k * P + pid];

        float py = (float)(h + k / 3 - 1) + o_y;
        float px = (float)(w + k % 3 - 1) + o_x;

        float y0f = floorf(py), x0f = floorf(px);
        float wy = py - y0f, wx = px - x0f;
        int y0 = (int)y0f, x0 = (int)x0f;
        int y1 = y0 + 1,  x1 = x0 + 1;

        bool vy0 = (unsigned)y0 < (unsigned)H;
        bool vy1 = (unsigned)y1 < (unsigned)H;
        bool vx0 = (unsigned)x0 < (unsigned)W;
        bool vx1 = (unsigned)x1 < (unsigned)W;

        int cy0 = min(max(y0, 0), H - 1) * W;
        int cy1 = min(max(y1, 0), H - 1) * W;
        int cx0 = min(max(x0, 0), W - 1);
        int cx1 = min(max(x1, 0), W - 1);

        // fold validity and mask into the 4 corner weights
        float a00 = (vy0 && vx0) ? (1.f - wy) * (1.f - wx) * m : 0.f;
        float a01 = (vy0 && vx1) ? (1.f - wy) * wx * m         : 0.f;
        float a10 = (vy1 && vx0) ? wy * (1.f - wx) * m         : 0.f;
        float a11 = (vy1 && vx1) ? wy * wx * m                 : 0.f;

        int o00 = cy0 + cx0, o01 = cy0 + cx1, o10 = cy1 + cx0, o11 = cy1 + cx1;

        const float* dwk = dwT + k * C * C;
#pragma unroll 4
        for (int c = 0; c < C; ++c) {
            const float* xc = xn + c * HW;
            float s = xc[o00] * a00;
            s = fmaf(xc[o01], a01, s);
            s = fmaf(xc[o10], a10, s);
            s = fmaf(xc[o11], a11, s);
            const float* wp = dwk + c * C;   // uniform, contiguous 48 floats
#pragma unroll
            for (int o = 0; o < C; ++o) acc[o] = fmaf(s, wp[o], acc[o]);
        }
    }

    int base = n * C * HW + hw;
#pragma unroll
    for (int o = 0; o < C; ++o) {
        float scale = gamma[o] / sqrtf(rvar[o] + BN_EPS);
        float v = fmaf(acc[o] - rmean[o], scale, beta[o]);
        v += x[base + o * HW];
        out[base + o * HW] = fmaxf(v, 0.f);
    }
}

// ---------------------------------------------------------------------------
extern "C" void kernel_launch(void* const* d_in, const int* in_sizes, int n_in,
                              void* d_out, int out_size, void* d_ws, size_t ws_size,
                              hipStream_t stream)
{
    const float* x     = (const float*)d_in[0];
    const float* tm_w  = (const float*)d_in[1];
    const float* tm_b  = (const float*)d_in[2];
    const float* tr_w  = (const float*)d_in[3];
    const float* tr_b  = (const float*)d_in[4];
    const float* mk_w  = (const float*)d_in[5];
    const float* mk_b  = (const float*)d_in[6];
    const float* dw    = (const float*)d_in[7];
    const float* gamma = (const float*)d_in[8];
    const float* beta  = (const float*)d_in[9];
    const float* rmean = (const float*)d_in[10];
    const float* rvar  = (const float*)d_in[11];
    float* out = (float*)d_out;
    float* ws  = (float*)d_ws;

    hipLaunchKernelGGL(prep_kernel, dim3((DWT_SZ + 255) / 256), dim3(256), 0, stream,
                       tm_w, tr_w, mk_w, dw, ws);
    hipLaunchKernelGGL(conv15_kernel, dim3(P / 256), dim3(256), 0, stream,
                       x, tm_b, tr_b, mk_b, ws);
    hipLaunchKernelGGL(deform_kernel, dim3(P / 256), dim3(256), 0, stream,
                       x, ws, gamma, beta, rmean, rvar, out);
}